// Round 3
// baseline (78.675 us; speedup 1.0000x reference)
//
#include <hip/hip_runtime.h>

#define TK 80    // TOKEN_DIM
#define TN 384   // EMB_DIM
#define BM 64    // rows per block

typedef __attribute__((ext_vector_type(8)))  __bf16 bf16x8;
typedef __attribute__((ext_vector_type(16))) float  f32x16;

// round-to-nearest-even f32 -> bf16 bits
__device__ __forceinline__ unsigned short f2bf_bits(float f) {
    unsigned int u = __float_as_uint(f);
    return (unsigned short)((u + 0x7fffu + ((u >> 16) & 1u)) >> 16);
}

union BF8 { unsigned short u[8]; bf16x8 v; };

__device__ __forceinline__ bf16x8 pack8(float4 f0, float4 f1) {
    BF8 r;
    r.u[0] = f2bf_bits(f0.x); r.u[1] = f2bf_bits(f0.y);
    r.u[2] = f2bf_bits(f0.z); r.u[3] = f2bf_bits(f0.w);
    r.u[4] = f2bf_bits(f1.x); r.u[5] = f2bf_bits(f1.y);
    r.u[6] = f2bf_bits(f1.z); r.u[7] = f2bf_bits(f1.w);
    return r.v;
}

// ---------------------------------------------------------------------------
// Fused kernel. Block = 4 waves = 64 out-rows; wave w owns cols [96w, 96w+96).
// MFMA transposed: A = W fragment (a-rows = out cols), B = feat fragment
// (b-cols = out rows), so D's reg axis = out cols -> float4 epilogue stores,
// and mask is lane-local (no shfl). No LDS, no barriers beyond the probe.
// Also writes the three passthrough outputs (amask/bidx rows of this block;
// block 0 writes gidx) -- single launch, no inter-kernel dependency.
// ---------------------------------------------------------------------------
__global__ __launch_bounds__(256) void tok_fused(
    const float* __restrict__ feat,
    const unsigned char* __restrict__ amask,
    const int* __restrict__ gidx,
    const int* __restrict__ bidx,
    const float* __restrict__ W,
    const float* __restrict__ bias,
    const float* __restrict__ cls,
    float* __restrict__ out,
    float* __restrict__ out_amask,
    float* __restrict__ out_gidx,
    float* __restrict__ out_bidx,
    int B, int T)
{
    const int tid   = threadIdx.x;
    const int lane  = tid & 63;
    const int wave  = tid >> 6;
    const int row0  = blockIdx.x * BM;
    const int colb  = wave * 96;
    const int lrow  = lane & 31;   // B-col / D-col -> out row within tile
    const int khalf = lane >> 5;   // 8-wide k half selector

    // ---- amask storage detection (bool bytes vs int32): probe first 1 KB
    const unsigned int* w32 = (const unsigned int*)amask;
    unsigned int wprobe = w32[tid & 255];
    int bytemode = __syncthreads_or((int)((wprobe & 0xFFFFFF00u) != 0u));

    // ---- passthrough outputs for this block's rows
    if (tid < BM) {
        int r = row0 + tid;
        out_amask[r] = bytemode ? (float)amask[r] : (float)(w32[r] & 1u);
        out_bidx[r]  = (float)bidx[r];
    }
    if (blockIdx.x == 0 && tid < B) out_gidx[tid] = (float)gidx[tid];

    // ---- per-lane mask for my out-rows
    float mymask[2];
    #pragma unroll
    for (int mt = 0; mt < 2; ++mt) {
        int r = row0 + mt * 32 + lrow;
        mymask[mt] = bytemode ? (float)amask[r] : (float)(w32[r] & 1u);
    }

    // ---- feat fragment loads first (HBM) so they overlap the W convert
    float4 ff0[5][2], ff1[5][2];
    #pragma unroll
    for (int ks = 0; ks < 5; ++ks)
        #pragma unroll
        for (int mt = 0; mt < 2; ++mt) {
            const float* p = feat + (size_t)(row0 + mt * 32 + lrow) * TK
                           + ks * 16 + khalf * 8;
            ff0[ks][mt] = *(const float4*)p;
            ff1[ks][mt] = *(const float4*)(p + 4);
        }

    // ---- W fragments (A operand): lane = out-col (lane&31), k-half = lane>>5
    bf16x8 wfrag[3][5];
    #pragma unroll
    for (int nt = 0; nt < 3; ++nt) {
        const float* wrow = W + (size_t)(colb + nt * 32 + lrow) * TK;
        #pragma unroll
        for (int ks = 0; ks < 5; ++ks) {
            const float* p = wrow + ks * 16 + khalf * 8;
            wfrag[nt][ks] = pack8(*(const float4*)p, *(const float4*)(p + 4));
        }
    }

    // ---- convert feat fragments
    bf16x8 ffrag[5][2];
    #pragma unroll
    for (int ks = 0; ks < 5; ++ks)
        #pragma unroll
        for (int mt = 0; mt < 2; ++mt)
            ffrag[ks][mt] = pack8(ff0[ks][mt], ff1[ks][mt]);

    // ---- MFMA: D[outcol, outrow], acc regs hold 4 consecutive out cols
    f32x16 acc[2][3];
    #pragma unroll
    for (int mt = 0; mt < 2; ++mt)
        #pragma unroll
        for (int nt = 0; nt < 3; ++nt)
            acc[mt][nt] = (f32x16)0.0f;

    #pragma unroll
    for (int ks = 0; ks < 5; ++ks)
        #pragma unroll
        for (int mt = 0; mt < 2; ++mt)
            #pragma unroll
            for (int nt = 0; nt < 3; ++nt)
                acc[mt][nt] = __builtin_amdgcn_mfma_f32_32x32x16_bf16(
                    wfrag[nt][ks], ffrag[ks][mt], acc[mt][nt], 0, 0, 0);

    // ---- bias per (nt, q): col = colb + nt*32 + 8q + 4*khalf
    float4 bv[3][4];
    #pragma unroll
    for (int nt = 0; nt < 3; ++nt)
        #pragma unroll
        for (int q = 0; q < 4; ++q)
            bv[nt][q] = *(const float4*)(bias + colb + nt * 32 + 8 * q + 4 * khalf);

    // ---- epilogue: row = row0 + mt*32 + (lane&31); float4 stores
    #pragma unroll
    for (int mt = 0; mt < 2; ++mt) {
        const int row = row0 + mt * 32 + lrow;
        const float m = mymask[mt];
        const bool iscls = (row % T) == 0;
        float* orow = out + (size_t)row * TN;
        #pragma unroll
        for (int nt = 0; nt < 3; ++nt) {
            #pragma unroll
            for (int q = 0; q < 4; ++q) {
                const int col = colb + nt * 32 + 8 * q + 4 * khalf;
                float4 v;
                v.x = m * (acc[mt][nt][4 * q + 0] + bv[nt][q].x);
                v.y = m * (acc[mt][nt][4 * q + 1] + bv[nt][q].y);
                v.z = m * (acc[mt][nt][4 * q + 2] + bv[nt][q].z);
                v.w = m * (acc[mt][nt][4 * q + 3] + bv[nt][q].w);
                if (iscls) v = *(const float4*)(cls + col);
                *(float4*)(orow + col) = v;
            }
        }
    }
}

extern "C" void kernel_launch(void* const* d_in, const int* in_sizes, int n_in,
                              void* d_out, int out_size, void* d_ws, size_t ws_size,
                              hipStream_t stream) {
    const float*         feat  = (const float*)d_in[0];
    const unsigned char* amask = (const unsigned char*)d_in[1];
    const int*           gidx  = (const int*)d_in[2];
    const int*           bidx  = (const int*)d_in[3];
    const float*         W     = (const float*)d_in[4];
    const float*         bias  = (const float*)d_in[5];
    const float*         cls   = (const float*)d_in[6];

    const int BT = in_sizes[1];        // B*T rows (131072)
    const int B  = in_sizes[2];        // 16
    const int T  = BT / B;             // 8192

    float* out       = (float*)d_out;                  // [BT, 384]
    float* out_amask = out + (size_t)BT * TN;          // [BT]
    float* out_gidx  = out_amask + BT;                 // [B]
    float* out_bidx  = out_gidx + B;                   // [BT]

    tok_fused<<<BT / BM, 256, 0, stream>>>(
        feat, amask, gidx, bidx, W, bias, cls,
        out, out_amask, out_gidx, out_bidx, B, T);
}

// Round 4
// 60.757 us; speedup vs baseline: 1.2949x; 1.2949x over previous
//
#include <hip/hip_runtime.h>

#define TK 80    // TOKEN_DIM
#define TN 384   // EMB_DIM
#define BM 64    // rows per block

typedef __attribute__((ext_vector_type(8)))  __bf16 bf16x8;
typedef __attribute__((ext_vector_type(16))) float  f32x16;

// f32x8 -> bf16x8 via compiler-native converts (v_cvt_pk_bf16_f32 on gfx950)
__device__ __forceinline__ bf16x8 pack8(float4 f0, float4 f1) {
    bf16x8 r;
    r[0] = (__bf16)f0.x; r[1] = (__bf16)f0.y;
    r[2] = (__bf16)f0.z; r[3] = (__bf16)f0.w;
    r[4] = (__bf16)f1.x; r[5] = (__bf16)f1.y;
    r[6] = (__bf16)f1.z; r[7] = (__bf16)f1.w;
    return r;
}

// ---------------------------------------------------------------------------
// Fused kernel, round-2 MFMA orientation (the coalesced-store one):
//   A = feat frag (rows = out rows), B = W frag (cols = out cols)
//   D: col = lane&31 -> out col (lane axis = consecutive cols, coalesced
//      128-B store segments), row = (reg&3)+8*(reg>>2)+4*khalf -> out row.
// Block = 4 waves = 64 out rows; wave w owns out cols [96w, 96w+96).
// K = 80 = 5 x 16 exact. No LDS tiles, no barriers except the probe's.
// Fragments are loaded + converted per k-step (keeps VGPR ~150).
// Also writes the three passthrough outputs; single launch.
// ---------------------------------------------------------------------------
__global__ __launch_bounds__(256) void tok_fused(
    const float* __restrict__ feat,
    const unsigned char* __restrict__ amask,
    const int* __restrict__ gidx,
    const int* __restrict__ bidx,
    const float* __restrict__ W,
    const float* __restrict__ bias,
    const float* __restrict__ cls,
    float* __restrict__ out,
    float* __restrict__ out_amask,
    float* __restrict__ out_gidx,
    float* __restrict__ out_bidx,
    int B, int T)
{
    const int tid   = threadIdx.x;
    const int lane  = tid & 63;
    const int wave  = tid >> 6;
    const int row0  = blockIdx.x * BM;
    const int colb  = wave * 96;
    const int lrow  = lane & 31;   // A-row (out row) / B-col (out col) in tile
    const int khalf = lane >> 5;   // 8-wide k-half selector

    // ---- amask storage detection (bool bytes vs int32): probe first 1 KB
    const unsigned int* w32 = (const unsigned int*)amask;
    unsigned int wprobe = w32[tid & 255];
    int bytemode = __syncthreads_or((int)((wprobe & 0xFFFFFF00u) != 0u));

    // ---- passthrough outputs for this block's rows
    if (tid < BM) {
        int r = row0 + tid;
        out_amask[r] = bytemode ? (float)amask[r] : (float)(w32[r] & 1u);
        out_bidx[r]  = (float)bidx[r];
    }
    if (blockIdx.x == 0 && tid < B) out_gidx[tid] = (float)gidx[tid];

    // ---- mask row vector: lane holds mask of row row0+lane (shfl later)
    float mv;
    {
        int r = row0 + lane;
        mv = bytemode ? (float)amask[r] : (float)(w32[r] & 1u);
    }

    // ---- bias / cls for my out cols (lane = out col within each nt tile)
    float bv[3], cv[3];
    #pragma unroll
    for (int nt = 0; nt < 3; ++nt) {
        int c = colb + nt * 32 + lrow;
        bv[nt] = bias[c];
        cv[nt] = cls[c];
    }

    // ---- main loop over K: load+convert fragments per k-step, 6 MFMAs
    f32x16 acc[2][3];
    #pragma unroll
    for (int mt = 0; mt < 2; ++mt)
        #pragma unroll
        for (int nt = 0; nt < 3; ++nt)
            acc[mt][nt] = (f32x16)0.0f;

    #pragma unroll
    for (int ks = 0; ks < 5; ++ks) {
        const int koff = ks * 16 + khalf * 8;

        bf16x8 af[2];
        #pragma unroll
        for (int mt = 0; mt < 2; ++mt) {
            const float* p = feat + (size_t)(row0 + mt * 32 + lrow) * TK + koff;
            af[mt] = pack8(*(const float4*)p, *(const float4*)(p + 4));
        }

        bf16x8 wf[3];
        #pragma unroll
        for (int nt = 0; nt < 3; ++nt) {
            const float* p = W + (size_t)(colb + nt * 32 + lrow) * TK + koff;
            wf[nt] = pack8(*(const float4*)p, *(const float4*)(p + 4));
        }

        #pragma unroll
        for (int mt = 0; mt < 2; ++mt)
            #pragma unroll
            for (int nt = 0; nt < 3; ++nt)
                acc[mt][nt] = __builtin_amdgcn_mfma_f32_32x32x16_bf16(
                    af[mt], wf[nt], acc[mt][nt], 0, 0, 0);
    }

    // ---- epilogue: row = row0 + mt*32 + 4*khalf + (reg&3) + 8*(reg>>2)
    //      lane axis = out col -> coalesced 128-B segments per store
    #pragma unroll
    for (int mt = 0; mt < 2; ++mt) {
        #pragma unroll
        for (int reg = 0; reg < 16; ++reg) {
            const int rlocal = mt * 32 + 4 * khalf + (reg & 3) + 8 * (reg >> 2);
            const float m = __shfl(mv, rlocal);
            const int row = row0 + rlocal;
            const bool iscls = (row % T) == 0;
            float* orow = out + (size_t)row * TN;
            #pragma unroll
            for (int nt = 0; nt < 3; ++nt) {
                float v = m * (acc[mt][nt][reg] + bv[nt]);
                if (iscls) v = cv[nt];
                orow[colb + nt * 32 + lrow] = v;
            }
        }
    }
}

extern "C" void kernel_launch(void* const* d_in, const int* in_sizes, int n_in,
                              void* d_out, int out_size, void* d_ws, size_t ws_size,
                              hipStream_t stream) {
    const float*         feat  = (const float*)d_in[0];
    const unsigned char* amask = (const unsigned char*)d_in[1];
    const int*           gidx  = (const int*)d_in[2];
    const int*           bidx  = (const int*)d_in[3];
    const float*         W     = (const float*)d_in[4];
    const float*         bias  = (const float*)d_in[5];
    const float*         cls   = (const float*)d_in[6];

    const int BT = in_sizes[1];        // B*T rows (131072)
    const int B  = in_sizes[2];        // 16
    const int T  = BT / B;             // 8192

    float* out       = (float*)d_out;                  // [BT, 384]
    float* out_amask = out + (size_t)BT * TN;          // [BT]
    float* out_gidx  = out_amask + BT;                 // [B]
    float* out_bidx  = out_gidx + B;                   // [BT]

    tok_fused<<<BT / BM, 256, 0, stream>>>(
        feat, amask, gidx, bidx, W, bias, cls,
        out, out_amask, out_gidx, out_bidx, B, T);
}